// Round 5
// baseline (99.608 us; speedup 1.0000x reference)
//
#include <hip/hip_runtime.h>
#include <hip/hip_bf16.h>

#define Bimg 32
#define Mgt 256
#define Nprop 4000
#define KBOX (Nprop + Mgt)   // 4256
#define NCLS 80
#define BATCH 512
#define NFG_CAP 128
#define NBINS 1024
#define BINCAP 1024
#define MT 16                 // m-rows per block
#define MS (Mgt / MT)         // 16 m-slices
#define KCH ((KBOX + 1023) / 1024)  // 5 column chunks (256 thr * 4 cols)

typedef float f32x4 __attribute__((ext_vector_type(4)));
typedef unsigned long long ull;

// ---------------- Kernel A: IoU tiles + atomicMax argmax ----------------
__global__ __launch_bounds__(256) void iou_part_kernel(
    const float* __restrict__ gt_boxes,     // [B,M,4]
    const float* __restrict__ prop_boxes,   // [B,N,4]
    float* __restrict__ out_iou,            // [B,M,K]
    ull* __restrict__ gpart)                // [B,K] packed argmax keys
{
    const int b  = blockIdx.z;
    const int ms = blockIdx.y;
    const int m0 = ms * MT;
    const int k0 = (blockIdx.x * 256 + threadIdx.x) * 4;

    __shared__ float4 gbox[MT];
    __shared__ float  garea[MT];
    if (threadIdx.x < MT) {
        float4 g = ((const float4*)(gt_boxes + (size_t)b * Mgt * 4))[m0 + threadIdx.x];
        gbox[threadIdx.x] = g;
        garea[threadIdx.x] = (g.z - g.x) * (g.w - g.y);
    }
    __syncthreads();
    if (k0 >= KBOX) return;

    float4 bx[4]; float a2[4];
    if (k0 < Nprop) {   // Nprop % 4 == 0 -> no straddle
        const float4* pp = (const float4*)(prop_boxes + (size_t)b * Nprop * 4);
        #pragma unroll
        for (int c = 0; c < 4; ++c) bx[c] = pp[k0 + c];
    } else {
        const float4* gg = (const float4*)(gt_boxes + (size_t)b * Mgt * 4);
        #pragma unroll
        for (int c = 0; c < 4; ++c) bx[c] = gg[k0 - Nprop + c];
    }
    #pragma unroll
    for (int c = 0; c < 4; ++c) a2[c] = (bx[c].z - bx[c].x) * (bx[c].w - bx[c].y);

    float bestv[4] = {-1.f, -1.f, -1.f, -1.f};
    int   bestm[4] = {0, 0, 0, 0};
    float* orow = out_iou + (size_t)b * Mgt * KBOX + (size_t)m0 * KBOX + k0;

    for (int mm = 0; mm < MT; ++mm) {
        float4 g = gbox[mm];
        float ga = garea[mm];
        float io[4];
        #pragma unroll
        for (int c = 0; c < 4; ++c) {
            float ltx = fmaxf(g.x, bx[c].x), lty = fmaxf(g.y, bx[c].y);
            float rbx = fminf(g.z, bx[c].z), rby = fminf(g.w, bx[c].w);
            float w = fmaxf(rbx - ltx, 0.0f);
            float h = fmaxf(rby - lty, 0.0f);
            float inter = w * h;
            float uni = ga + a2[c] - inter;
            float iou = (inter > 0.0f) ? (inter / uni) : 0.0f;
            io[c] = iou;
            if (iou > bestv[c]) { bestv[c] = iou; bestm[c] = m0 + mm; } // strict > == first-argmax
        }
        f32x4 res = { io[0], io[1], io[2], io[3] };
        __builtin_nontemporal_store(res, (f32x4*)(orow + (size_t)mm * KBOX));
    }

    ull* pr = gpart + (size_t)b * KBOX + k0;
    #pragma unroll
    for (int c = 0; c < 4; ++c) {
        ull key = ((ull)__float_as_uint(bestv[c]) << 8) |
                  (ull)(255 - bestm[c]);       // max-key == (max iou, min m)
        atomicMax(pr + c, key);
    }
}

// ---------------- Kernel B: decode + histogram-select + rank-order ----------------
__global__ __launch_bounds__(1024) void sample_kernel(
    const int*   __restrict__ gt_classes,   // [B,M]
    const float* __restrict__ pri,          // [B,K]
    const ull*   __restrict__ gpart,        // [B,K]
    float* __restrict__ out_midx,           // [B,K]
    float* __restrict__ out_mlab,           // [B,K]
    float* __restrict__ out_idx,            // [B,512]
    float* __restrict__ out_lab)            // [B,512]
{
    const int b    = blockIdx.x;
    const int tid  = threadIdx.x;
    const int lane = tid & 63;
    const int wv   = tid >> 6;              // 16 waves

    __shared__ ull keys[KBOX];                    // 34 KB
    __shared__ unsigned char selA[KBOX];          // 4.25 KB
    __shared__ int histP[NBINS];                  // fg low16 | bg high16
    __shared__ int sufP[NBINS + 1];
    __shared__ ull binFG[BINCAP];                 // 8 KB
    __shared__ ull binBG[BINCAP];                 // 8 KB
    __shared__ __align__(16) ull selKeys[BATCH + 2];
    __shared__ int waveTot[16], waveOff[16];
    __shared__ int cntF, cntB, cntSel, sTF, sTB;

    histP[tid] = 0;
    if (tid == 0) { cntF = 0; cntB = 0; cntSel = 0; sTF = -1; sTB = -1; }
    __syncthreads();

    // decode argmax, write midx/mlab, build keys + histogram
    for (int i = tid; i < KBOX; i += 1024) {
        float p  = pri[(size_t)b * KBOX + i];
        ull  bk  = gpart[(size_t)b * KBOX + i];
        float v  = __uint_as_float((unsigned)(bk >> 8));
        int   mi = 255 - (int)(bk & 0xFFull);
        bool  fg = (v >= 0.5f);
        int  cls = fg ? gt_classes[b * Mgt + mi] : NCLS;
        out_midx[(size_t)b * KBOX + i] = (float)mi;
        out_mlab[(size_t)b * KBOX + i] = fg ? 1.0f : 0.0f;
        unsigned pb = __float_as_uint(p);   // pri in [0,1): monotone as uint
        // key: pri | (idx asc tiebreak) | class payload (never reached in compare)
        keys[i] = ((ull)pb << 32) |
                  ((ull)(0xFFFFu - (unsigned)i) << 16) |
                  ((ull)(unsigned)cls << 8);
        selA[i] = 0;
        int bucket = (int)(p * (float)NBINS);
        bucket = min(max(bucket, 0), NBINS - 1);
        atomicAdd(&histP[bucket], fg ? 1 : (1 << 16));
    }
    __syncthreads();

    // inclusive suffix scan of packed histogram: wave shfl + cross-wave
    int v = histP[tid];
    #pragma unroll
    for (int off = 1; off < 64; off <<= 1) {
        int o = __shfl_down(v, off);
        if (lane + off < 64) v += o;
    }
    if (lane == 0) waveTot[wv] = v;   // wave total (suffix at lane 0)
    __syncthreads();
    if (wv == 0) {
        int t = (lane < 16) ? waveTot[lane] : 0;
        #pragma unroll
        for (int off = 1; off < 64; off <<= 1) {
            int o = __shfl_down(t, off);
            if (lane + off < 64) t += o;
        }
        if (lane < 16) waveOff[lane] = t - waveTot[lane];  // strict suffix
    }
    __syncthreads();
    sufP[tid] = v + waveOff[wv];
    if (tid == 0) sufP[NBINS] = 0;
    __syncthreads();

    const int total_fg = sufP[0] & 0xFFFF;
    const int total_bg = (sufP[0] >> 16) & 0xFFFF;
    const int num_fg = min(total_fg, NFG_CAP);
    const int num_bg = min(total_bg, BATCH - num_fg);

    {
        int sf  = sufP[tid] & 0xFFFF;
        int sfn = sufP[tid + 1] & 0xFFFF;
        if (num_fg > 0 && sf >= num_fg && sfn < num_fg) sTF = tid;
        int sb  = (sufP[tid] >> 16) & 0xFFFF;
        int sbn = (sufP[tid + 1] >> 16) & 0xFFFF;
        if (num_bg > 0 && sb >= num_bg && sbn < num_bg) sTB = tid;
    }
    __syncthreads();
    const int tF = sTF, tB = sTB;
    const int aboveF = (tF >= 0) ? (sufP[tF + 1] & 0xFFFF) : 0;
    const int aboveB = (tB >= 0) ? ((sufP[tB + 1] >> 16) & 0xFFFF) : 0;
    const int needF = num_fg - aboveF;
    const int needB = num_bg - aboveB;

    // selection: above threshold bin -> selected; in threshold bin -> collect
    for (int i = tid; i < KBOX; i += 1024) {
        ull key = keys[i];
        float p = __uint_as_float((unsigned)(key >> 32));
        int bucket = (int)(p * (float)NBINS);
        bucket = min(max(bucket, 0), NBINS - 1);
        bool fg = ((unsigned)(key >> 8) & 0xFFu) < NCLS;
        if (fg) {
            if (tF >= 0) {
                if (bucket > tF) selA[i] = 1;
                else if (bucket == tF) { int j = atomicAdd(&cntF, 1); if (j < BINCAP) binFG[j] = key; }
            }
        } else {
            if (tB >= 0) {
                if (bucket > tB) selA[i] = 1;
                else if (bucket == tB) { int j = atomicAdd(&cntB, 1); if (j < BINCAP) binBG[j] = key; }
            }
        }
    }
    __syncthreads();

    // exact rank inside threshold bins (keys distinct)
    {
        int cf = min(cntF, BINCAP);
        for (int j = tid; j < cf; j += 1024) {
            ull key = binFG[j];
            int rank = 0;
            for (int l = 0; l < cf; ++l) rank += (binFG[l] > key) ? 1 : 0;
            if (rank < needF) { unsigned kk = 0xFFFFu - (unsigned)((key >> 16) & 0xFFFFu); selA[kk] = 1; }
        }
        int cb = min(cntB, BINCAP);
        for (int j = tid; j < cb; j += 1024) {
            ull key = binBG[j];
            int rank = 0;
            for (int l = 0; l < cb; ++l) rank += (binBG[l] > key) ? 1 : 0;
            if (rank < needB) { unsigned kk = 0xFFFFu - (unsigned)((key >> 16) & 0xFFFFu); selA[kk] = 1; }
        }
    }
    __syncthreads();

    // compact selected keys
    for (int i = tid; i < KBOX; i += 1024) {
        if (selA[i]) {
            int p = atomicAdd(&cntSel, 1);
            selKeys[p] = keys[i];
        }
    }
    __syncthreads();
    const int ns = cntSel;      // == num_fg + num_bg
    if (tid == 0) { selKeys[ns] = 0ull; selKeys[ns + 1] = 0ull; }  // pad for vec reads
    __syncthreads();

    // order by rank-counting (no barriers, LDS broadcast reads)
    if (tid < ns) {
        ull key = selKeys[tid];
        int rank = 0;
        const int n2 = (ns + 1) & ~1;
        for (int l = 0; l < n2; l += 2) {
            ulonglong2 two = *(const ulonglong2*)&selKeys[l];
            rank += (two.x > key) ? 1 : 0;
            rank += (two.y > key) ? 1 : 0;
        }
        unsigned kk = 0xFFFFu - (unsigned)((key >> 16) & 0xFFFFu);
        int cls = (int)((key >> 8) & 0xFFu);
        out_idx[b * BATCH + rank] = (float)kk;
        out_lab[b * BATCH + rank] = (float)cls;
    }

    // tail padding (labels = -1): lowest-index non-selected (dormant when ns==512)
    if (ns < BATCH) {
        __syncthreads();
        int loc[5]; int acc = 0;
        #pragma unroll
        for (int q = 0; q < 5; ++q) {
            int i = tid * 5 + q;
            int contrib = (i < KBOX && !selA[i]) ? 1 : 0;
            loc[q] = acc; acc += contrib;
        }
        histP[tid] = acc;
        __syncthreads();
        for (int off = 1; off < 1024; off <<= 1) {
            int vv = histP[tid];
            int add = (tid >= off) ? histP[tid - off] : 0;
            __syncthreads();
            histP[tid] = vv + add;
            __syncthreads();
        }
        int excl = tid ? histP[tid - 1] : 0;
        #pragma unroll
        for (int q = 0; q < 5; ++q) {
            int i = tid * 5 + q;
            if (i < KBOX && !selA[i]) {
                int p = ns + excl + loc[q];
                if (p < BATCH) { out_idx[b * BATCH + p] = (float)i; out_lab[b * BATCH + p] = -1.0f; }
            }
        }
    }
}

extern "C" void kernel_launch(void* const* d_in, const int* in_sizes, int n_in,
                              void* d_out, int out_size, void* d_ws, size_t ws_size,
                              hipStream_t stream) {
    const float* gt_boxes   = (const float*)d_in[0];
    const float* prop_boxes = (const float*)d_in[1];
    const int*   gt_classes = (const int*)d_in[2];
    const float* rand_pri   = (const float*)d_in[3];

    float* out = (float*)d_out;
    const size_t off_iou  = 0;
    const size_t off_midx = (size_t)Bimg * Mgt * KBOX;
    const size_t off_mlab = off_midx + (size_t)Bimg * KBOX;
    const size_t off_idx  = off_mlab + (size_t)Bimg * KBOX;
    const size_t off_lab  = off_idx  + (size_t)Bimg * BATCH;

    ull* gpart = (ull*)d_ws;   // [B,K] = 1.09 MB

    hipMemsetAsync(gpart, 0, (size_t)Bimg * KBOX * sizeof(ull), stream);

    dim3 gridA(KCH, MS, Bimg);   // 5 x 16 x 32 = 2560 blocks
    iou_part_kernel<<<gridA, 256, 0, stream>>>(
        gt_boxes, prop_boxes, out + off_iou, gpart);

    sample_kernel<<<Bimg, 1024, 0, stream>>>(
        gt_classes, rand_pri, gpart,
        out + off_midx, out + off_mlab,
        out + off_idx, out + off_lab);
}

// Round 6
// 65.335 us; speedup vs baseline: 1.5246x; 1.5246x over previous
//
#include <hip/hip_runtime.h>
#include <hip/hip_bf16.h>

#define Bimg 32
#define Mgt 256
#define Nprop 4000
#define KBOX (Nprop + Mgt)   // 4256
#define NCLS 80
#define BATCH 512
#define NFG_CAP 128
#define NBINS 1024
#define BINCAP 1024
#define MT 32                 // m-rows per block
#define MS (Mgt / MT)         // 8 m-slices
#define KCH ((KBOX + 1023) / 1024)  // 5 column chunks (256 thr * 4 cols)

typedef float f32x4 __attribute__((ext_vector_type(4)));
typedef unsigned long long ull;

// ---------------- Kernel A: IoU tiles + per-slice partial argmax (plain stores) ----------------
__global__ __launch_bounds__(256) void iou_part_kernel(
    const float* __restrict__ gt_boxes,     // [B,M,4]
    const float* __restrict__ prop_boxes,   // [B,N,4]
    float* __restrict__ out_iou,            // [B,M,K]
    ull* __restrict__ part)                 // [B,MS,K] packed keys
{
    const int b  = blockIdx.z;
    const int ms = blockIdx.y;
    const int m0 = ms * MT;
    const int k0 = (blockIdx.x * 256 + threadIdx.x) * 4;

    __shared__ float4 gbox[MT];
    __shared__ float  garea[MT];
    if (threadIdx.x < MT) {
        float4 g = ((const float4*)(gt_boxes + (size_t)b * Mgt * 4))[m0 + threadIdx.x];
        gbox[threadIdx.x] = g;
        garea[threadIdx.x] = (g.z - g.x) * (g.w - g.y);
    }
    __syncthreads();
    if (k0 >= KBOX) return;

    float4 bx[4]; float a2[4];
    if (k0 < Nprop) {   // Nprop % 4 == 0 -> no straddle
        const float4* pp = (const float4*)(prop_boxes + (size_t)b * Nprop * 4);
        #pragma unroll
        for (int c = 0; c < 4; ++c) bx[c] = pp[k0 + c];
    } else {
        const float4* gg = (const float4*)(gt_boxes + (size_t)b * Mgt * 4);
        #pragma unroll
        for (int c = 0; c < 4; ++c) bx[c] = gg[k0 - Nprop + c];
    }
    #pragma unroll
    for (int c = 0; c < 4; ++c) a2[c] = (bx[c].z - bx[c].x) * (bx[c].w - bx[c].y);

    float bestv[4] = {-1.f, -1.f, -1.f, -1.f};
    int   bestm[4] = {0, 0, 0, 0};
    float* orow = out_iou + (size_t)b * Mgt * KBOX + (size_t)m0 * KBOX + k0;

    for (int mm = 0; mm < MT; ++mm) {
        float4 g = gbox[mm];
        float ga = garea[mm];
        float io[4];
        #pragma unroll
        for (int c = 0; c < 4; ++c) {
            float ltx = fmaxf(g.x, bx[c].x), lty = fmaxf(g.y, bx[c].y);
            float rbx = fminf(g.z, bx[c].z), rby = fminf(g.w, bx[c].w);
            float w = fmaxf(rbx - ltx, 0.0f);
            float h = fmaxf(rby - lty, 0.0f);
            float inter = w * h;
            float uni = ga + a2[c] - inter;
            float iou = (inter > 0.0f) ? (inter / uni) : 0.0f;
            io[c] = iou;
            if (iou > bestv[c]) { bestv[c] = iou; bestm[c] = m0 + mm; } // strict > == first-argmax
        }
        f32x4 res = { io[0], io[1], io[2], io[3] };
        *(f32x4*)(orow + (size_t)mm * KBOX) = res;
    }

    ull* pr = part + ((size_t)b * MS + ms) * KBOX + k0;
    ull bk[4];
    #pragma unroll
    for (int c = 0; c < 4; ++c)
        bk[c] = ((ull)__float_as_uint(bestv[c]) << 8) |
                (ull)(255 - bestm[c]);         // max-key == (max iou, min m)
    *(ulonglong2*)(pr)     = make_ulonglong2(bk[0], bk[1]);
    *(ulonglong2*)(pr + 2) = make_ulonglong2(bk[2], bk[3]);
}

// ---------------- Kernel B: reduce + decode + histogram-select + rank-order ----------------
__global__ __launch_bounds__(1024) void sample_kernel(
    const int*   __restrict__ gt_classes,   // [B,M]
    const float* __restrict__ pri,          // [B,K]
    const ull*   __restrict__ part,         // [B,MS,K]
    float* __restrict__ out_midx,           // [B,K]
    float* __restrict__ out_mlab,           // [B,K]
    float* __restrict__ out_idx,            // [B,512]
    float* __restrict__ out_lab)            // [B,512]
{
    const int b    = blockIdx.x;
    const int tid  = threadIdx.x;
    const int lane = tid & 63;
    const int wv   = tid >> 6;              // 16 waves

    __shared__ ull keys[KBOX];                    // 34 KB
    __shared__ unsigned char selA[KBOX];          // 4.25 KB
    __shared__ int gcls[Mgt];                     // 1 KB
    __shared__ int histP[NBINS];                  // fg low16 | bg high16
    __shared__ int sufP[NBINS + 1];
    __shared__ ull binFG[BINCAP];                 // 8 KB
    __shared__ ull binBG[BINCAP];                 // 8 KB
    __shared__ __align__(16) ull selKeys[BATCH + 2];
    __shared__ int waveTot[16], waveOff[16];
    __shared__ int cntF, cntB, cntSel, sTF, sTB;

    histP[tid] = 0;
    if (tid < Mgt) gcls[tid] = gt_classes[b * Mgt + tid];
    if (tid == 0) { cntF = 0; cntB = 0; cntSel = 0; sTF = -1; sTB = -1; }
    __syncthreads();

    // reduce partials, decode argmax, write midx/mlab, build keys + histogram
    for (int i = tid; i < KBOX; i += 1024) {
        float p  = pri[(size_t)b * KBOX + i];
        ull bk = part[(size_t)b * MS * KBOX + i];
        #pragma unroll
        for (int s = 1; s < MS; ++s) {
            ull k2 = part[((size_t)b * MS + s) * KBOX + i];
            if (k2 > bk) bk = k2;
        }
        float v  = __uint_as_float((unsigned)(bk >> 8));
        int   mi = 255 - (int)(bk & 0xFFull);
        bool  fg = (v >= 0.5f);
        int  cls = fg ? gcls[mi] : NCLS;
        out_midx[(size_t)b * KBOX + i] = (float)mi;
        out_mlab[(size_t)b * KBOX + i] = fg ? 1.0f : 0.0f;
        unsigned pb = __float_as_uint(p);   // pri in [0,1): monotone as uint
        // key: pri | (idx asc tiebreak) | class payload (never decides a compare)
        keys[i] = ((ull)pb << 32) |
                  ((ull)(0xFFFFu - (unsigned)i) << 16) |
                  ((ull)(unsigned)cls << 8);
        selA[i] = 0;
        int bucket = (int)(p * (float)NBINS);
        bucket = min(max(bucket, 0), NBINS - 1);
        atomicAdd(&histP[bucket], fg ? 1 : (1 << 16));
    }
    __syncthreads();

    // inclusive suffix scan of packed histogram: wave shfl + cross-wave
    int v = histP[tid];
    #pragma unroll
    for (int off = 1; off < 64; off <<= 1) {
        int o = __shfl_down(v, off);
        if (lane + off < 64) v += o;
    }
    if (lane == 0) waveTot[wv] = v;   // wave total (suffix at lane 0)
    __syncthreads();
    if (wv == 0) {
        int t = (lane < 16) ? waveTot[lane] : 0;
        #pragma unroll
        for (int off = 1; off < 64; off <<= 1) {
            int o = __shfl_down(t, off);
            if (lane + off < 64) t += o;
        }
        if (lane < 16) waveOff[lane] = t - waveTot[lane];  // strict suffix
    }
    __syncthreads();
    sufP[tid] = v + waveOff[wv];
    if (tid == 0) sufP[NBINS] = 0;
    __syncthreads();

    const int total_fg = sufP[0] & 0xFFFF;
    const int total_bg = (sufP[0] >> 16) & 0xFFFF;
    const int num_fg = min(total_fg, NFG_CAP);
    const int num_bg = min(total_bg, BATCH - num_fg);

    {
        int sf  = sufP[tid] & 0xFFFF;
        int sfn = sufP[tid + 1] & 0xFFFF;
        if (num_fg > 0 && sf >= num_fg && sfn < num_fg) sTF = tid;
        int sb  = (sufP[tid] >> 16) & 0xFFFF;
        int sbn = (sufP[tid + 1] >> 16) & 0xFFFF;
        if (num_bg > 0 && sb >= num_bg && sbn < num_bg) sTB = tid;
    }
    __syncthreads();
    const int tF = sTF, tB = sTB;
    const int aboveF = (tF >= 0) ? (sufP[tF + 1] & 0xFFFF) : 0;
    const int aboveB = (tB >= 0) ? ((sufP[tB + 1] >> 16) & 0xFFFF) : 0;
    const int needF = num_fg - aboveF;
    const int needB = num_bg - aboveB;

    // selection: above threshold bin -> selected; in threshold bin -> collect
    for (int i = tid; i < KBOX; i += 1024) {
        ull key = keys[i];
        float p = __uint_as_float((unsigned)(key >> 32));
        int bucket = (int)(p * (float)NBINS);
        bucket = min(max(bucket, 0), NBINS - 1);
        bool fg = ((unsigned)(key >> 8) & 0xFFu) < NCLS;
        if (fg) {
            if (tF >= 0) {
                if (bucket > tF) selA[i] = 1;
                else if (bucket == tF) { int j = atomicAdd(&cntF, 1); if (j < BINCAP) binFG[j] = key; }
            }
        } else {
            if (tB >= 0) {
                if (bucket > tB) selA[i] = 1;
                else if (bucket == tB) { int j = atomicAdd(&cntB, 1); if (j < BINCAP) binBG[j] = key; }
            }
        }
    }
    __syncthreads();

    // exact rank inside threshold bins (keys distinct)
    {
        int cf = min(cntF, BINCAP);
        for (int j = tid; j < cf; j += 1024) {
            ull key = binFG[j];
            int rank = 0;
            for (int l = 0; l < cf; ++l) rank += (binFG[l] > key) ? 1 : 0;
            if (rank < needF) { unsigned kk = 0xFFFFu - (unsigned)((key >> 16) & 0xFFFFu); selA[kk] = 1; }
        }
        int cb = min(cntB, BINCAP);
        for (int j = tid; j < cb; j += 1024) {
            ull key = binBG[j];
            int rank = 0;
            for (int l = 0; l < cb; ++l) rank += (binBG[l] > key) ? 1 : 0;
            if (rank < needB) { unsigned kk = 0xFFFFu - (unsigned)((key >> 16) & 0xFFFFu); selA[kk] = 1; }
        }
    }
    __syncthreads();

    // compact selected keys
    for (int i = tid; i < KBOX; i += 1024) {
        if (selA[i]) {
            int p = atomicAdd(&cntSel, 1);
            selKeys[p] = keys[i];
        }
    }
    __syncthreads();
    const int ns = cntSel;      // == num_fg + num_bg
    if (tid == 0) { selKeys[ns] = 0ull; selKeys[ns + 1] = 0ull; }  // pad for vec reads
    __syncthreads();

    // order by rank-counting (no barriers, LDS broadcast reads)
    if (tid < ns) {
        ull key = selKeys[tid];
        int rank = 0;
        const int n2 = (ns + 1) & ~1;
        for (int l = 0; l < n2; l += 2) {
            ulonglong2 two = *(const ulonglong2*)&selKeys[l];
            rank += (two.x > key) ? 1 : 0;
            rank += (two.y > key) ? 1 : 0;
        }
        unsigned kk = 0xFFFFu - (unsigned)((key >> 16) & 0xFFFFu);
        int cls = (int)((key >> 8) & 0xFFu);
        out_idx[b * BATCH + rank] = (float)kk;
        out_lab[b * BATCH + rank] = (float)cls;
    }

    // tail padding (labels = -1): lowest-index non-selected (dormant when ns==512)
    if (ns < BATCH) {
        __syncthreads();
        int loc[5]; int acc = 0;
        #pragma unroll
        for (int q = 0; q < 5; ++q) {
            int i = tid * 5 + q;
            int contrib = (i < KBOX && !selA[i]) ? 1 : 0;
            loc[q] = acc; acc += contrib;
        }
        histP[tid] = acc;
        __syncthreads();
        for (int off = 1; off < 1024; off <<= 1) {
            int vv = histP[tid];
            int add = (tid >= off) ? histP[tid - off] : 0;
            __syncthreads();
            histP[tid] = vv + add;
            __syncthreads();
        }
        int excl = tid ? histP[tid - 1] : 0;
        #pragma unroll
        for (int q = 0; q < 5; ++q) {
            int i = tid * 5 + q;
            if (i < KBOX && !selA[i]) {
                int p = ns + excl + loc[q];
                if (p < BATCH) { out_idx[b * BATCH + p] = (float)i; out_lab[b * BATCH + p] = -1.0f; }
            }
        }
    }
}

extern "C" void kernel_launch(void* const* d_in, const int* in_sizes, int n_in,
                              void* d_out, int out_size, void* d_ws, size_t ws_size,
                              hipStream_t stream) {
    const float* gt_boxes   = (const float*)d_in[0];
    const float* prop_boxes = (const float*)d_in[1];
    const int*   gt_classes = (const int*)d_in[2];
    const float* rand_pri   = (const float*)d_in[3];

    float* out = (float*)d_out;
    const size_t off_iou  = 0;
    const size_t off_midx = (size_t)Bimg * Mgt * KBOX;
    const size_t off_mlab = off_midx + (size_t)Bimg * KBOX;
    const size_t off_idx  = off_mlab + (size_t)Bimg * KBOX;
    const size_t off_lab  = off_idx  + (size_t)Bimg * BATCH;

    ull* part = (ull*)d_ws;   // [B,MS,K] = 8.7 MB, fully overwritten each call

    dim3 gridA(KCH, MS, Bimg);   // 5 x 8 x 32 = 1280 blocks
    iou_part_kernel<<<gridA, 256, 0, stream>>>(
        gt_boxes, prop_boxes, out + off_iou, part);

    sample_kernel<<<Bimg, 1024, 0, stream>>>(
        gt_classes, rand_pri, part,
        out + off_midx, out + off_mlab,
        out + off_idx, out + off_lab);
}

// Round 7
// 60.038 us; speedup vs baseline: 1.6591x; 1.0882x over previous
//
#include <hip/hip_runtime.h>
#include <hip/hip_bf16.h>

#define Bimg 32
#define Mgt 256
#define Nprop 4000
#define KBOX (Nprop + Mgt)   // 4256
#define NCLS 80
#define BATCH 512
#define NFG_CAP 128
#define NBINS 1024
#define BINCAP 1024
#define MT 32                 // m-rows per block
#define MS (Mgt / MT)         // 8 m-slices
#define CPT 2                 // columns per thread
#define KCH ((KBOX + 256*CPT - 1) / (256*CPT))  // 9 column chunks

typedef float f32x2 __attribute__((ext_vector_type(2)));
typedef unsigned long long ull;

// ---------------- Kernel A: IoU tiles + per-slice partial argmax ----------------
__global__ __launch_bounds__(256) void iou_part_kernel(
    const float* __restrict__ gt_boxes,     // [B,M,4]
    const float* __restrict__ prop_boxes,   // [B,N,4]
    float* __restrict__ out_iou,            // [B,M,K]
    ull* __restrict__ part)                 // [B,MS,K] packed keys
{
    const int b  = blockIdx.z;
    const int ms = blockIdx.y;
    const int m0 = ms * MT;
    const int k0 = (blockIdx.x * 256 + threadIdx.x) * CPT;

    __shared__ float4 gbox[MT];
    __shared__ float  garea[MT];
    if (threadIdx.x < MT) {
        float4 g = ((const float4*)(gt_boxes + (size_t)b * Mgt * 4))[m0 + threadIdx.x];
        gbox[threadIdx.x] = g;
        garea[threadIdx.x] = (g.z - g.x) * (g.w - g.y);
    }
    __syncthreads();
    if (k0 >= KBOX) return;

    float4 bx[CPT]; float a2[CPT];
    if (k0 < Nprop) {   // k0 even, Nprop even -> no straddle
        const float4* pp = (const float4*)(prop_boxes + (size_t)b * Nprop * 4);
        #pragma unroll
        for (int c = 0; c < CPT; ++c) bx[c] = pp[k0 + c];
    } else {
        const float4* gg = (const float4*)(gt_boxes + (size_t)b * Mgt * 4);
        #pragma unroll
        for (int c = 0; c < CPT; ++c) bx[c] = gg[k0 - Nprop + c];
    }
    #pragma unroll
    for (int c = 0; c < CPT; ++c) a2[c] = (bx[c].z - bx[c].x) * (bx[c].w - bx[c].y);

    float bestv[CPT]; int bestm[CPT];
    #pragma unroll
    for (int c = 0; c < CPT; ++c) { bestv[c] = -1.f; bestm[c] = 0; }
    float* orow = out_iou + (size_t)b * Mgt * KBOX + (size_t)m0 * KBOX + k0;

    for (int mm = 0; mm < MT; ++mm) {
        float4 g = gbox[mm];
        float ga = garea[mm];
        float io[CPT];
        #pragma unroll
        for (int c = 0; c < CPT; ++c) {
            float ltx = fmaxf(g.x, bx[c].x), lty = fmaxf(g.y, bx[c].y);
            float rbx = fminf(g.z, bx[c].z), rby = fminf(g.w, bx[c].w);
            float w = fmaxf(rbx - ltx, 0.0f);
            float h = fmaxf(rby - lty, 0.0f);
            float inter = w * h;
            float uni = ga + a2[c] - inter;
            float iou = (inter > 0.0f) ? (inter / uni) : 0.0f;
            io[c] = iou;
            if (iou > bestv[c]) { bestv[c] = iou; bestm[c] = m0 + mm; } // strict > == first-argmax
        }
        f32x2 res = { io[0], io[1] };
        *(f32x2*)(orow + (size_t)mm * KBOX) = res;
    }

    ull* pr = part + ((size_t)b * MS + ms) * KBOX + k0;
    ull bk0 = ((ull)__float_as_uint(bestv[0]) << 8) | (ull)(255 - bestm[0]);
    ull bk1 = ((ull)__float_as_uint(bestv[1]) << 8) | (ull)(255 - bestm[1]);
    *(ulonglong2*)pr = make_ulonglong2(bk0, bk1);   // max-key == (max iou, min m)
}

// ---------------- Kernel B: reduce + decode + histogram-select + rank-order ----------------
__global__ __launch_bounds__(1024) void sample_kernel(
    const int*   __restrict__ gt_classes,   // [B,M]
    const float* __restrict__ pri,          // [B,K]
    const ull*   __restrict__ part,         // [B,MS,K]
    float* __restrict__ out_midx,           // [B,K]
    float* __restrict__ out_mlab,           // [B,K]
    float* __restrict__ out_idx,            // [B,512]
    float* __restrict__ out_lab)            // [B,512]
{
    const int b    = blockIdx.x;
    const int tid  = threadIdx.x;
    const int lane = tid & 63;
    const int wv   = tid >> 6;              // 16 waves

    __shared__ ull keys[KBOX];                    // 34 KB
    __shared__ unsigned char selA[KBOX];          // 4.25 KB
    __shared__ int gcls[Mgt];                     // 1 KB
    __shared__ int histP[NBINS];                  // fg low16 | bg high16
    __shared__ int sufP[NBINS + 1];
    __shared__ ull binFG[BINCAP];                 // 8 KB
    __shared__ ull binBG[BINCAP];                 // 8 KB
    __shared__ __align__(16) ull selKeys[BATCH + 2];
    __shared__ int waveTot[16], waveOff[16];
    __shared__ int cntF, cntB, cntSel, sTF, sTB;

    histP[tid] = 0;
    if (tid < Mgt) gcls[tid] = gt_classes[b * Mgt + tid];
    if (tid == 0) { cntF = 0; cntB = 0; cntSel = 0; sTF = -1; sTB = -1; }
    __syncthreads();

    // reduce partials, decode argmax, write midx/mlab, build keys + histogram
    for (int i = tid; i < KBOX; i += 1024) {
        float p  = pri[(size_t)b * KBOX + i];
        ull bk = part[(size_t)b * MS * KBOX + i];
        #pragma unroll
        for (int s = 1; s < MS; ++s) {
            ull k2 = part[((size_t)b * MS + s) * KBOX + i];
            if (k2 > bk) bk = k2;
        }
        float v  = __uint_as_float((unsigned)(bk >> 8));
        int   mi = 255 - (int)(bk & 0xFFull);
        bool  fg = (v >= 0.5f);
        int  cls = fg ? gcls[mi] : NCLS;
        out_midx[(size_t)b * KBOX + i] = (float)mi;
        out_mlab[(size_t)b * KBOX + i] = fg ? 1.0f : 0.0f;
        unsigned pb = __float_as_uint(p);   // pri in [0,1): monotone as uint
        // key: pri | (idx asc tiebreak) | class payload (never decides a compare)
        keys[i] = ((ull)pb << 32) |
                  ((ull)(0xFFFFu - (unsigned)i) << 16) |
                  ((ull)(unsigned)cls << 8);
        selA[i] = 0;
        int bucket = (int)(p * (float)NBINS);
        bucket = min(max(bucket, 0), NBINS - 1);
        atomicAdd(&histP[bucket], fg ? 1 : (1 << 16));
    }
    __syncthreads();

    // inclusive suffix scan of packed histogram: wave shfl + cross-wave
    int v = histP[tid];
    #pragma unroll
    for (int off = 1; off < 64; off <<= 1) {
        int o = __shfl_down(v, off);
        if (lane + off < 64) v += o;
    }
    if (lane == 0) waveTot[wv] = v;   // wave total (suffix at lane 0)
    __syncthreads();
    if (wv == 0) {
        int t = (lane < 16) ? waveTot[lane] : 0;
        #pragma unroll
        for (int off = 1; off < 64; off <<= 1) {
            int o = __shfl_down(t, off);
            if (lane + off < 64) t += o;
        }
        if (lane < 16) waveOff[lane] = t - waveTot[lane];  // strict suffix
    }
    __syncthreads();
    sufP[tid] = v + waveOff[wv];
    if (tid == 0) sufP[NBINS] = 0;
    __syncthreads();

    const int total_fg = sufP[0] & 0xFFFF;
    const int total_bg = (sufP[0] >> 16) & 0xFFFF;
    const int num_fg = min(total_fg, NFG_CAP);
    const int num_bg = min(total_bg, BATCH - num_fg);

    {
        int sf  = sufP[tid] & 0xFFFF;
        int sfn = sufP[tid + 1] & 0xFFFF;
        if (num_fg > 0 && sf >= num_fg && sfn < num_fg) sTF = tid;
        int sb  = (sufP[tid] >> 16) & 0xFFFF;
        int sbn = (sufP[tid + 1] >> 16) & 0xFFFF;
        if (num_bg > 0 && sb >= num_bg && sbn < num_bg) sTB = tid;
    }
    __syncthreads();
    const int tF = sTF, tB = sTB;
    const int aboveF = (tF >= 0) ? (sufP[tF + 1] & 0xFFFF) : 0;
    const int aboveB = (tB >= 0) ? ((sufP[tB + 1] >> 16) & 0xFFFF) : 0;
    const int needF = num_fg - aboveF;
    const int needB = num_bg - aboveB;

    // selection: above threshold bin -> selected; in threshold bin -> collect
    for (int i = tid; i < KBOX; i += 1024) {
        ull key = keys[i];
        float p = __uint_as_float((unsigned)(key >> 32));
        int bucket = (int)(p * (float)NBINS);
        bucket = min(max(bucket, 0), NBINS - 1);
        bool fg = ((unsigned)(key >> 8) & 0xFFu) < NCLS;
        if (fg) {
            if (tF >= 0) {
                if (bucket > tF) selA[i] = 1;
                else if (bucket == tF) { int j = atomicAdd(&cntF, 1); if (j < BINCAP) binFG[j] = key; }
            }
        } else {
            if (tB >= 0) {
                if (bucket > tB) selA[i] = 1;
                else if (bucket == tB) { int j = atomicAdd(&cntB, 1); if (j < BINCAP) binBG[j] = key; }
            }
        }
    }
    __syncthreads();

    // exact rank inside threshold bins (keys distinct)
    {
        int cf = min(cntF, BINCAP);
        for (int j = tid; j < cf; j += 1024) {
            ull key = binFG[j];
            int rank = 0;
            for (int l = 0; l < cf; ++l) rank += (binFG[l] > key) ? 1 : 0;
            if (rank < needF) { unsigned kk = 0xFFFFu - (unsigned)((key >> 16) & 0xFFFFu); selA[kk] = 1; }
        }
        int cb = min(cntB, BINCAP);
        for (int j = tid; j < cb; j += 1024) {
            ull key = binBG[j];
            int rank = 0;
            for (int l = 0; l < cb; ++l) rank += (binBG[l] > key) ? 1 : 0;
            if (rank < needB) { unsigned kk = 0xFFFFu - (unsigned)((key >> 16) & 0xFFFFu); selA[kk] = 1; }
        }
    }
    __syncthreads();

    // compact selected keys
    for (int i = tid; i < KBOX; i += 1024) {
        if (selA[i]) {
            int p = atomicAdd(&cntSel, 1);
            selKeys[p] = keys[i];
        }
    }
    __syncthreads();
    const int ns = cntSel;      // == num_fg + num_bg
    if (tid == 0) { selKeys[ns] = 0ull; selKeys[ns + 1] = 0ull; }  // pad for vec reads
    __syncthreads();

    // order by rank-counting (no barriers, LDS broadcast reads)
    if (tid < ns) {
        ull key = selKeys[tid];
        int rank = 0;
        const int n2 = (ns + 1) & ~1;
        for (int l = 0; l < n2; l += 2) {
            ulonglong2 two = *(const ulonglong2*)&selKeys[l];
            rank += (two.x > key) ? 1 : 0;
            rank += (two.y > key) ? 1 : 0;
        }
        unsigned kk = 0xFFFFu - (unsigned)((key >> 16) & 0xFFFFu);
        int cls = (int)((key >> 8) & 0xFFu);
        out_idx[b * BATCH + rank] = (float)kk;
        out_lab[b * BATCH + rank] = (float)cls;
    }

    // tail padding (labels = -1): lowest-index non-selected (dormant when ns==512)
    if (ns < BATCH) {
        __syncthreads();
        int loc[5]; int acc = 0;
        #pragma unroll
        for (int q = 0; q < 5; ++q) {
            int i = tid * 5 + q;
            int contrib = (i < KBOX && !selA[i]) ? 1 : 0;
            loc[q] = acc; acc += contrib;
        }
        histP[tid] = acc;
        __syncthreads();
        for (int off = 1; off < 1024; off <<= 1) {
            int vv = histP[tid];
            int add = (tid >= off) ? histP[tid - off] : 0;
            __syncthreads();
            histP[tid] = vv + add;
            __syncthreads();
        }
        int excl = tid ? histP[tid - 1] : 0;
        #pragma unroll
        for (int q = 0; q < 5; ++q) {
            int i = tid * 5 + q;
            if (i < KBOX && !selA[i]) {
                int p = ns + excl + loc[q];
                if (p < BATCH) { out_idx[b * BATCH + p] = (float)i; out_lab[b * BATCH + p] = -1.0f; }
            }
        }
    }
}

extern "C" void kernel_launch(void* const* d_in, const int* in_sizes, int n_in,
                              void* d_out, int out_size, void* d_ws, size_t ws_size,
                              hipStream_t stream) {
    const float* gt_boxes   = (const float*)d_in[0];
    const float* prop_boxes = (const float*)d_in[1];
    const int*   gt_classes = (const int*)d_in[2];
    const float* rand_pri   = (const float*)d_in[3];

    float* out = (float*)d_out;
    const size_t off_iou  = 0;
    const size_t off_midx = (size_t)Bimg * Mgt * KBOX;
    const size_t off_mlab = off_midx + (size_t)Bimg * KBOX;
    const size_t off_idx  = off_mlab + (size_t)Bimg * KBOX;
    const size_t off_lab  = off_idx  + (size_t)Bimg * BATCH;

    ull* part = (ull*)d_ws;   // [B,MS,K] = 8.7 MB, fully overwritten each call

    dim3 gridA(KCH, MS, Bimg);   // 9 x 8 x 32 = 2304 blocks (~8 resident/CU)
    iou_part_kernel<<<gridA, 256, 0, stream>>>(
        gt_boxes, prop_boxes, out + off_iou, part);

    sample_kernel<<<Bimg, 1024, 0, stream>>>(
        gt_classes, rand_pri, part,
        out + off_midx, out + off_mlab,
        out + off_idx, out + off_lab);
}

// Round 9
// 57.659 us; speedup vs baseline: 1.7275x; 1.0413x over previous
//
#include <hip/hip_runtime.h>
#include <hip/hip_bf16.h>

#define Bimg 32
#define Mgt 256
#define Nprop 4000
#define KBOX (Nprop + Mgt)   // 4256
#define NCLS 80
#define BATCH 512
#define NFG_CAP 128
#define NBINS 1024
#define BINCAP 1024
#define MT 32                 // m-rows per block
#define MS (Mgt / MT)         // 8 m-slices
#define CPT 2                 // columns per thread (kernel A)
#define KCH ((KBOX + 256*CPT - 1) / (256*CPT))  // 9 column chunks (A)
#define KCHB ((KBOX + 511) / 512)               // 9 chunks (decode, 2/thread)

typedef float f32x2 __attribute__((ext_vector_type(2)));
typedef unsigned long long ull;

// ---------------- Kernel A: IoU tiles + per-slice partial argmax ----------------
__global__ __launch_bounds__(256) void iou_part_kernel(
    const float* __restrict__ gt_boxes,     // [B,M,4]
    const float* __restrict__ prop_boxes,   // [B,N,4]
    float* __restrict__ out_iou,            // [B,M,K]
    ull* __restrict__ part)                 // [B,MS,K] packed keys
{
    const int b  = blockIdx.z;
    const int ms = blockIdx.y;
    const int m0 = ms * MT;
    const int k0 = (blockIdx.x * 256 + threadIdx.x) * CPT;

    __shared__ float4 gbox[MT];
    __shared__ float  garea[MT];
    if (threadIdx.x < MT) {
        float4 g = ((const float4*)(gt_boxes + (size_t)b * Mgt * 4))[m0 + threadIdx.x];
        gbox[threadIdx.x] = g;
        garea[threadIdx.x] = (g.z - g.x) * (g.w - g.y);
    }
    __syncthreads();
    if (k0 >= KBOX) return;

    float4 bx[CPT]; float a2[CPT];
    if (k0 < Nprop) {   // k0 even, Nprop even -> no straddle
        const float4* pp = (const float4*)(prop_boxes + (size_t)b * Nprop * 4);
        #pragma unroll
        for (int c = 0; c < CPT; ++c) bx[c] = pp[k0 + c];
    } else {
        const float4* gg = (const float4*)(gt_boxes + (size_t)b * Mgt * 4);
        #pragma unroll
        for (int c = 0; c < CPT; ++c) bx[c] = gg[k0 - Nprop + c];
    }
    #pragma unroll
    for (int c = 0; c < CPT; ++c) a2[c] = (bx[c].z - bx[c].x) * (bx[c].w - bx[c].y);

    float bestv[CPT]; int bestm[CPT];
    #pragma unroll
    for (int c = 0; c < CPT; ++c) { bestv[c] = -1.f; bestm[c] = 0; }
    float* orow = out_iou + (size_t)b * Mgt * KBOX + (size_t)m0 * KBOX + k0;

    for (int mm = 0; mm < MT; ++mm) {
        float4 g = gbox[mm];
        float ga = garea[mm];
        float io[CPT];
        #pragma unroll
        for (int c = 0; c < CPT; ++c) {
            float ltx = fmaxf(g.x, bx[c].x), lty = fmaxf(g.y, bx[c].y);
            float rbx = fminf(g.z, bx[c].z), rby = fminf(g.w, bx[c].w);
            float w = fmaxf(rbx - ltx, 0.0f);
            float h = fmaxf(rby - lty, 0.0f);
            float inter = w * h;
            float uni = ga + a2[c] - inter;
            // fast reciprocal + 1 Newton-Raphson step (error ~1-2 ulp; validated round 8)
            float r = __builtin_amdgcn_rcpf(uni);
            r = fmaf(fmaf(-uni, r, 1.0f), r, r);
            float iou = inter * r;
            iou = (inter > 0.0f) ? iou : 0.0f;
            io[c] = iou;
            if (iou > bestv[c]) { bestv[c] = iou; bestm[c] = m0 + mm; } // strict > == first-argmax
        }
        f32x2 res = { io[0], io[1] };
        *(f32x2*)(orow + (size_t)mm * KBOX) = res;
    }

    ull* pr = part + ((size_t)b * MS + ms) * KBOX + k0;
    ull bk0 = ((ull)__float_as_uint(bestv[0]) << 8) | (ull)(255 - bestm[0]);
    ull bk1 = ((ull)__float_as_uint(bestv[1]) << 8) | (ull)(255 - bestm[1]);
    *(ulonglong2*)pr = make_ulonglong2(bk0, bk1);   // max-key == (max iou, min m)
}

// ---------------- Kernel B1: parallel decode + keys + per-block histograms ----------------
__global__ __launch_bounds__(256) void decode_kernel(
    const int*   __restrict__ gt_classes,   // [B,M]
    const float* __restrict__ pri,          // [B,K]
    const ull*   __restrict__ part,         // [B,MS,K]
    float* __restrict__ out_midx,           // [B,K]
    float* __restrict__ out_mlab,           // [B,K]
    ull*   __restrict__ keysG,              // [B,K]
    int*   __restrict__ histG)              // [B,KCHB,NBINS] packed fg|bg
{
    const int b   = blockIdx.y;
    const int ch  = blockIdx.x;
    const int tid = threadIdx.x;

    __shared__ int histL[NBINS];
    __shared__ int gcls[Mgt];
    *(int4*)&histL[tid * 4] = make_int4(0, 0, 0, 0);
    gcls[tid] = gt_classes[b * Mgt + tid];
    __syncthreads();

    const int i0 = ch * 512 + tid * 2;
    if (i0 < KBOX) {
        const ull* p0 = part + (size_t)b * MS * KBOX + i0;
        ulonglong2 bk2 = *(const ulonglong2*)p0;
        ull bk[2] = { bk2.x, bk2.y };
        #pragma unroll
        for (int s = 1; s < MS; ++s) {
            ulonglong2 t = *(const ulonglong2*)(p0 + (size_t)s * KBOX);
            bk[0] = (t.x > bk[0]) ? t.x : bk[0];
            bk[1] = (t.y > bk[1]) ? t.y : bk[1];
        }
        f32x2 pv = *(const f32x2*)(pri + (size_t)b * KBOX + i0);
        float mi2[2], ml2[2]; ull kk[2];
        #pragma unroll
        for (int c = 0; c < 2; ++c) {
            float v  = __uint_as_float((unsigned)(bk[c] >> 8));
            int   mi = 255 - (int)(bk[c] & 0xFFull);
            bool  fg = (v >= 0.5f);
            int  cls = fg ? gcls[mi] : NCLS;
            mi2[c] = (float)mi;
            ml2[c] = fg ? 1.0f : 0.0f;
            float p = pv[c];
            unsigned pb = __float_as_uint(p);   // pri in [0,1): monotone as uint
            kk[c] = ((ull)pb << 32) |
                    ((ull)(0xFFFFu - (unsigned)(i0 + c)) << 16) |
                    ((ull)(unsigned)cls << 8);
            int bucket = (int)(p * (float)NBINS);
            bucket = min(max(bucket, 0), NBINS - 1);
            atomicAdd(&histL[bucket], fg ? 1 : (1 << 16));
        }
        *(f32x2*)(out_midx + (size_t)b * KBOX + i0) = f32x2{ mi2[0], mi2[1] };
        *(f32x2*)(out_mlab + (size_t)b * KBOX + i0) = f32x2{ ml2[0], ml2[1] };
        *(ulonglong2*)(keysG + (size_t)b * KBOX + i0) = make_ulonglong2(kk[0], kk[1]);
    }
    __syncthreads();
    int4 h = *(int4*)&histL[tid * 4];
    *(int4*)&histG[((size_t)(b * KCHB + ch)) * NBINS + tid * 4] = h;
}

// ---------------- Kernel B2: scan + select + rank-order (1 block / image) ----------------
__global__ __launch_bounds__(1024) void sample_kernel(
    const ull* __restrict__ keysG,          // [B,K]
    const int* __restrict__ histG,          // [B,KCHB,NBINS]
    float* __restrict__ out_idx,            // [B,512]
    float* __restrict__ out_lab)            // [B,512]
{
    const int b    = blockIdx.x;
    const int tid  = threadIdx.x;
    const int lane = tid & 63;
    const int wv   = tid >> 6;              // 16 waves

    __shared__ ull keys[KBOX];                    // 34 KB
    __shared__ unsigned char selA[KBOX];          // 4.25 KB
    __shared__ int sufP[NBINS + 1];
    __shared__ int scanT[NBINS];                  // tail scratch
    __shared__ ull binFG[BINCAP];                 // 8 KB
    __shared__ ull binBG[BINCAP];                 // 8 KB
    __shared__ __align__(16) ull selKeys[BATCH + 2];
    __shared__ int waveTot[16], waveOff[16];
    __shared__ int cntF, cntB, cntSel, sTF, sTB;

    // load keys + clear selA: strided, covers the 4256-elem array incl. tail
    for (int i0 = tid * 4; i0 < KBOX; i0 += 1024 * 4) {
        ulonglong2 a = *(const ulonglong2*)(keysG + (size_t)b * KBOX + i0);
        ulonglong2 c = *(const ulonglong2*)(keysG + (size_t)b * KBOX + i0 + 2);
        *(ulonglong2*)&keys[i0]     = a;
        *(ulonglong2*)&keys[i0 + 2] = c;
        *(uchar4*)&selA[i0] = make_uchar4(0, 0, 0, 0);
    }
    // histogram: sum per-chunk slices
    int hv = 0;
    #pragma unroll
    for (int c = 0; c < KCHB; ++c) hv += histG[((size_t)(b * KCHB + c)) * NBINS + tid];
    if (tid == 0) { cntF = 0; cntB = 0; cntSel = 0; sTF = -1; sTB = -1; }

    // inclusive suffix scan of packed histogram: wave shfl + cross-wave
    int v = hv;
    #pragma unroll
    for (int off = 1; off < 64; off <<= 1) {
        int o = __shfl_down(v, off);
        if (lane + off < 64) v += o;
    }
    if (lane == 0) waveTot[wv] = v;   // wave total (suffix at lane 0)
    __syncthreads();
    if (wv == 0) {
        int t = (lane < 16) ? waveTot[lane] : 0;
        #pragma unroll
        for (int off = 1; off < 64; off <<= 1) {
            int o = __shfl_down(t, off);
            if (lane + off < 64) t += o;
        }
        if (lane < 16) waveOff[lane] = t - waveTot[lane];  // strict suffix
    }
    __syncthreads();
    sufP[tid] = v + waveOff[wv];
    if (tid == 0) sufP[NBINS] = 0;
    __syncthreads();

    const int total_fg = sufP[0] & 0xFFFF;
    const int total_bg = (sufP[0] >> 16) & 0xFFFF;
    const int num_fg = min(total_fg, NFG_CAP);
    const int num_bg = min(total_bg, BATCH - num_fg);

    {
        int sf  = sufP[tid] & 0xFFFF;
        int sfn = sufP[tid + 1] & 0xFFFF;
        if (num_fg > 0 && sf >= num_fg && sfn < num_fg) sTF = tid;
        int sb  = (sufP[tid] >> 16) & 0xFFFF;
        int sbn = (sufP[tid + 1] >> 16) & 0xFFFF;
        if (num_bg > 0 && sb >= num_bg && sbn < num_bg) sTB = tid;
    }
    __syncthreads();
    const int tF = sTF, tB = sTB;
    const int aboveF = (tF >= 0) ? (sufP[tF + 1] & 0xFFFF) : 0;
    const int aboveB = (tB >= 0) ? ((sufP[tB + 1] >> 16) & 0xFFFF) : 0;
    const int needF = num_fg - aboveF;
    const int needB = num_bg - aboveB;

    // selection: above threshold bin -> selected; in threshold bin -> collect
    for (int i = tid; i < KBOX; i += 1024) {
        ull key = keys[i];
        float p = __uint_as_float((unsigned)(key >> 32));
        int bucket = (int)(p * (float)NBINS);
        bucket = min(max(bucket, 0), NBINS - 1);
        bool fg = ((unsigned)(key >> 8) & 0xFFu) < NCLS;
        if (fg) {
            if (tF >= 0) {
                if (bucket > tF) selA[i] = 1;
                else if (bucket == tF) { int j = atomicAdd(&cntF, 1); if (j < BINCAP) binFG[j] = key; }
            }
        } else {
            if (tB >= 0) {
                if (bucket > tB) selA[i] = 1;
                else if (bucket == tB) { int j = atomicAdd(&cntB, 1); if (j < BINCAP) binBG[j] = key; }
            }
        }
    }
    __syncthreads();

    // exact rank inside threshold bins (keys distinct)
    {
        int cf = min(cntF, BINCAP);
        for (int j = tid; j < cf; j += 1024) {
            ull key = binFG[j];
            int rank = 0;
            for (int l = 0; l < cf; ++l) rank += (binFG[l] > key) ? 1 : 0;
            if (rank < needF) { unsigned kk = 0xFFFFu - (unsigned)((key >> 16) & 0xFFFFu); selA[kk] = 1; }
        }
        int cb = min(cntB, BINCAP);
        for (int j = tid; j < cb; j += 1024) {
            ull key = binBG[j];
            int rank = 0;
            for (int l = 0; l < cb; ++l) rank += (binBG[l] > key) ? 1 : 0;
            if (rank < needB) { unsigned kk = 0xFFFFu - (unsigned)((key >> 16) & 0xFFFFu); selA[kk] = 1; }
        }
    }
    __syncthreads();

    // compact selected keys
    for (int i = tid; i < KBOX; i += 1024) {
        if (selA[i]) {
            int p = atomicAdd(&cntSel, 1);
            selKeys[p] = keys[i];
        }
    }
    __syncthreads();
    const int ns = cntSel;      // == num_fg + num_bg
    if (tid == 0) { selKeys[ns] = 0ull; selKeys[ns + 1] = 0ull; }  // pad for vec reads
    __syncthreads();

    // order by rank-counting (no barriers, LDS broadcast reads)
    if (tid < ns) {
        ull key = selKeys[tid];
        int rank = 0;
        const int n2 = (ns + 1) & ~1;
        for (int l = 0; l < n2; l += 2) {
            ulonglong2 two = *(const ulonglong2*)&selKeys[l];
            rank += (two.x > key) ? 1 : 0;
            rank += (two.y > key) ? 1 : 0;
        }
        unsigned kk = 0xFFFFu - (unsigned)((key >> 16) & 0xFFFFu);
        int cls = (int)((key >> 8) & 0xFFu);
        out_idx[b * BATCH + rank] = (float)kk;
        out_lab[b * BATCH + rank] = (float)cls;
    }

    // tail padding (labels = -1): lowest-index non-selected (dormant when ns==512)
    if (ns < BATCH) {
        __syncthreads();
        int loc[5]; int acc = 0;
        #pragma unroll
        for (int q = 0; q < 5; ++q) {
            int i = tid * 5 + q;
            int contrib = (i < KBOX && !selA[i]) ? 1 : 0;
            loc[q] = acc; acc += contrib;
        }
        scanT[tid] = acc;
        __syncthreads();
        for (int off = 1; off < 1024; off <<= 1) {
            int vv = scanT[tid];
            int add = (tid >= off) ? scanT[tid - off] : 0;
            __syncthreads();
            scanT[tid] = vv + add;
            __syncthreads();
        }
        int excl = tid ? scanT[tid - 1] : 0;
        #pragma unroll
        for (int q = 0; q < 5; ++q) {
            int i = tid * 5 + q;
            if (i < KBOX && !selA[i]) {
                int p = ns + excl + loc[q];
                if (p < BATCH) { out_idx[b * BATCH + p] = (float)i; out_lab[b * BATCH + p] = -1.0f; }
            }
        }
    }
}

extern "C" void kernel_launch(void* const* d_in, const int* in_sizes, int n_in,
                              void* d_out, int out_size, void* d_ws, size_t ws_size,
                              hipStream_t stream) {
    const float* gt_boxes   = (const float*)d_in[0];
    const float* prop_boxes = (const float*)d_in[1];
    const int*   gt_classes = (const int*)d_in[2];
    const float* rand_pri   = (const float*)d_in[3];

    float* out = (float*)d_out;
    const size_t off_iou  = 0;
    const size_t off_midx = (size_t)Bimg * Mgt * KBOX;
    const size_t off_mlab = off_midx + (size_t)Bimg * KBOX;
    const size_t off_idx  = off_mlab + (size_t)Bimg * KBOX;
    const size_t off_lab  = off_idx  + (size_t)Bimg * BATCH;

    // workspace layout (all fully overwritten every call)
    char* ws = (char*)d_ws;
    ull* part  = (ull*)ws;                                       // [B,MS,K]  8.72 MB
    ull* keysG = (ull*)(ws + (size_t)Bimg * MS * KBOX * 8);      // [B,K]     1.09 MB
    int* histG = (int*)(ws + (size_t)Bimg * MS * KBOX * 8
                           + (size_t)Bimg * KBOX * 8);           // [B,KCHB,NBINS] 1.18 MB

    dim3 gridA(KCH, MS, Bimg);   // 9 x 8 x 32 = 2304 blocks
    iou_part_kernel<<<gridA, 256, 0, stream>>>(
        gt_boxes, prop_boxes, out + off_iou, part);

    dim3 gridD(KCHB, Bimg);      // 9 x 32 = 288 blocks
    decode_kernel<<<gridD, 256, 0, stream>>>(
        gt_classes, rand_pri, part,
        out + off_midx, out + off_mlab, keysG, histG);

    sample_kernel<<<Bimg, 1024, 0, stream>>>(
        keysG, histG, out + off_idx, out + off_lab);
}